// Round 6
// baseline (255.376 us; speedup 1.0000x reference)
//
#include <hip/hip_runtime.h>
#include <hip/hip_bf16.h>

#define GH 64
#define LS 32
#define HF 32
#define DS 16

typedef short bf16x8 __attribute__((ext_vector_type(8)));
typedef float f32x4 __attribute__((ext_vector_type(4)));

#define MFMA16(a, b, c) __builtin_amdgcn_mfma_f32_16x16x32_bf16(a, b, c, 0, 0, 0)

__device__ __forceinline__ unsigned int f2bf_rne(float f) {
    unsigned int u = __float_as_uint(f);
    return (u + 0x7FFFu + ((u >> 16) & 1u)) >> 16;   // RNE (weights, loaded once)
}
__device__ __forceinline__ unsigned short f2bf_h(float f) {
    return (unsigned short)((__float_as_uint(f) + 0x8000u) >> 16);  // round-half-up, 2 inst
}
__device__ __forceinline__ unsigned int relu2(unsigned int w) {
    // packed bf16 max(w, 0): single v_pk_max instruction
    union { unsigned int u; __hip_bfloat162 v; } a, z, r;
    a.u = w; z.u = 0u;
    r.v = __hmax2(a.v, z.v);
    return r.u;
}
__device__ __forceinline__ float sigm(float x) {
    return __fdividef(1.0f, 1.0f + __expf(-x));
}
__device__ __forceinline__ float tanh_(float x) {
    return 1.0f - __fdividef(2.0f, __expf(2.0f * x) + 1.0f);
}

// A-fragment (16x16x32) from a 16x64 bf16 tile, XOR-swizzled 16B blocks:
// element (seq,ch) at seq*64 + (((ch>>3)^(seq&7))<<3) + (ch&7). Conflict-free
// b128 reads (R4/R5: SQ_LDS_BANK_CONFLICT ~ 0), 2-way-free b16 writes.
__device__ __forceinline__ bf16x8 ld_afrag(const unsigned short* base, int m,
                                           int quad, int half, bool relu) {
    int b   = half * 4 + quad;
    int idx = (m << 6) + ((b ^ (m & 7)) << 3);
    uint4 d = *reinterpret_cast<const uint4*>(base + idx);
    if (relu) { d.x = relu2(d.x); d.y = relu2(d.y); d.z = relu2(d.z); d.w = relu2(d.w); }
    union { uint4 u; bf16x8 v; } cv; cv.u = d;
    return cv.v;
}

// B-fragment: lane holds B[k=quad*8+j][n]; fp32 weights -> bf16 RNE (once).
__device__ __forceinline__ bf16x8 ld_bfrag(const float* __restrict__ W, int ldw,
                                           int col, int k0) {
    bf16x8 f;
    #pragma unroll
    for (int j = 0; j < 8; ++j)
        f[j] = (short)f2bf_rne(W[(k0 + j) * ldw + col]);
    return f;
}

// pack two f32 -> (bf16(v1)<<16)|bf16(v0) by truncation: single v_perm_b32
__device__ __forceinline__ unsigned int pack_trunc(float v0, float v1) {
    return __builtin_amdgcn_perm(__float_as_uint(v1), __float_as_uint(v0),
                                 0x07060302u);
}

// Layer-0 input A-frag built on the fly: relu(xv*siW[ch]+sib[ch]) for 8 chans.
__device__ __forceinline__ bf16x8 build_l0(float xv, const float* w, const float* b) {
    float4 w0 = reinterpret_cast<const float4*>(w)[0];
    float4 w1 = reinterpret_cast<const float4*>(w)[1];
    float4 b0 = reinterpret_cast<const float4*>(b)[0];
    float4 b1 = reinterpret_cast<const float4*>(b)[1];
    float v0 = fmaxf(fmaf(xv, w0.x, b0.x), 0.0f);
    float v1 = fmaxf(fmaf(xv, w0.y, b0.y), 0.0f);
    float v2 = fmaxf(fmaf(xv, w0.z, b0.z), 0.0f);
    float v3 = fmaxf(fmaf(xv, w0.w, b0.w), 0.0f);
    float v4 = fmaxf(fmaf(xv, w1.x, b1.x), 0.0f);
    float v5 = fmaxf(fmaf(xv, w1.y, b1.y), 0.0f);
    float v6 = fmaxf(fmaf(xv, w1.z, b1.z), 0.0f);
    float v7 = fmaxf(fmaf(xv, w1.w, b1.w), 0.0f);
    union { uint4 u; bf16x8 v; } cv;
    cv.u.x = pack_trunc(v0, v1);
    cv.u.y = pack_trunc(v2, v3);
    cv.u.z = pack_trunc(v4, v5);
    cv.u.w = pack_trunc(v6, v7);
    return cv.v;
}

// 1024 threads = 16 waves = (layer l: 0..3) x (col-tile jt: 0..3). Block owns
// TWO 16-seq groups (32 seqs): the resident B-fragments (the dominant register
// cost) are reused for both, halving block count to 250 -> ONE occupancy round
// (R5 ran 2 serial rounds: 1 block/CU at 128 regs/wave). Layer-pipelined GRU
// (step tau: layer l does t=tau-l; 2-slot ring/group; 1 barrier/step), then
// fused slow_out/s2s epilogue and fast diagonal SSM with overlap-add atomics.
__global__ __launch_bounds__(1024, 4) void slowfast_fused(
    const float* __restrict__ x,
    const float* __restrict__ siW,  const float* __restrict__ sib,
    const float* __restrict__ Wih,  const float* __restrict__ Whh,
    const float* __restrict__ bih,  const float* __restrict__ bhh,
    const float* __restrict__ soW,  const float* __restrict__ sob,
    const float* __restrict__ s2sW, const float* __restrict__ s2sb,
    const float* __restrict__ finW, const float* __restrict__ finb,
    const float* __restrict__ foutW, const float* __restrict__ foutb,
    float* __restrict__ out,
    int T, int ns, int BS)
{
    __shared__ __align__(16) unsigned short buf[2][4][2][16 * 64];  // 32 KB ring
    __shared__ float xs[2][16 * 33];   // x windows per group (pad-33)
    __shared__ float swb[128];         // siW[64] | sib[64]
    __shared__ float AG[32 * 65];      // A_s | g_s staging (pad-65)

    const int tid  = threadIdx.x;
    const int lane = tid & 63;
    const int wid  = tid >> 6;
    const int l    = wid >> 2;          // layer
    const int jt   = wid & 3;           // col tile
    const int c    = lane & 15;
    const int quad = lane >> 4;
    const int col  = jt * 16 + c;
    const int seqbase = blockIdx.x * 32;

    // ---- stage x windows (32 seqs x 32 t = 1024) + slow_in weights ----
    {
        int seq = tid >> 5, t = tid & 31;
        int q = seqbase + seq; if (q > BS - 1) q = BS - 1;
        int b  = (q >= ns) ? 1 : 0;
        int si = q - b * ns;
        xs[seq >> 4][(seq & 15) * 33 + t] = x[b * T + si * DS + t];
    }
    if (tid < 64) { swb[tid] = siW[tid]; swb[64 + tid] = sib[tid]; }

    // ---- per-wave resident B-fragments (loaded once; live in AGPRs) ----
    const float* Wi = Wih + (size_t)l * GH * 192;
    const float* Wh = Whh + (size_t)l * GH * 192;
    bf16x8 BiR[2], BiZ[2], BiN[2], BhR[2], BhZ[2], BhN[2];
    #pragma unroll
    for (int kc = 0; kc < 2; ++kc) {
        int k0 = kc * 32 + quad * 8;
        BiR[kc] = ld_bfrag(Wi, 192,       col, k0);
        BiZ[kc] = ld_bfrag(Wi, 192,  64 + col, k0);
        BiN[kc] = ld_bfrag(Wi, 192, 128 + col, k0);
        BhR[kc] = ld_bfrag(Wh, 192,       col, k0);
        BhZ[kc] = ld_bfrag(Wh, 192,  64 + col, k0);
        BhN[kc] = ld_bfrag(Wh, 192, 128 + col, k0);
    }
    float bR  = bih[l * 192 + col]      + bhh[l * 192 + col];
    float bZ  = bih[l * 192 + 64 + col] + bhh[l * 192 + 64 + col];
    float bNI = bih[l * 192 + 128 + col];   // n-gate ih/hh separate:
    float bNH = bhh[l * 192 + 128 + col];   // tanh(xg_n + r*hg_n)

    float hprev[2][4] = {{0,0,0,0},{0,0,0,0}};

    __syncthreads();

    // ---- pipelined main loop: one barrier per global step, 2 groups/step ----
    #pragma unroll 1
    for (int tau = 0; tau < LS + 3; ++tau) {
        int t = tau - l;
        if (t >= 0 && t < LS) {
            #pragma unroll
            for (int grp = 0; grp < 2; ++grp) {
                bf16x8 a0, a1, h0, h1;
                if (l == 0) {
                    float xv = xs[grp][c * 33 + t];
                    a0 = build_l0(xv, &swb[quad * 8],      &swb[64 + quad * 8]);
                    a1 = build_l0(xv, &swb[32 + quad * 8], &swb[96 + quad * 8]);
                } else {
                    const unsigned short* ab = buf[grp][l - 1][t & 1];
                    a0 = ld_afrag(ab, c, quad, 0, true);    // relu(prev-layer h)
                    a1 = ld_afrag(ab, c, quad, 1, true);
                }
                if (t > 0) {
                    const unsigned short* hb = buf[grp][l][(t - 1) & 1];
                    h0 = ld_afrag(hb, c, quad, 0, false);   // pre-relu recurrent
                    h1 = ld_afrag(hb, c, quad, 1, false);
                }
                f32x4 aR  = (f32x4){bR,  bR,  bR,  bR};
                f32x4 aZ  = (f32x4){bZ,  bZ,  bZ,  bZ};
                f32x4 aNI = (f32x4){bNI, bNI, bNI, bNI};
                f32x4 aNH = (f32x4){bNH, bNH, bNH, bNH};
                aR  = MFMA16(a0, BiR[0], aR);
                aR  = MFMA16(a1, BiR[1], aR);
                aZ  = MFMA16(a0, BiZ[0], aZ);
                aZ  = MFMA16(a1, BiZ[1], aZ);
                aNI = MFMA16(a0, BiN[0], aNI);
                aNI = MFMA16(a1, BiN[1], aNI);
                if (t > 0) {
                    aR  = MFMA16(h0, BhR[0], aR);
                    aR  = MFMA16(h1, BhR[1], aR);
                    aZ  = MFMA16(h0, BhZ[0], aZ);
                    aZ  = MFMA16(h1, BhZ[1], aZ);
                    aNH = MFMA16(h0, BhN[0], aNH);
                    aNH = MFMA16(h1, BhN[1], aNH);
                }
                unsigned short* wb = buf[grp][l][t & 1];
                #pragma unroll
                for (int i = 0; i < 4; ++i) {
                    float r  = sigm(aR[i]);
                    float z  = sigm(aZ[i]);
                    float n  = tanh_(fmaf(r, aNH[i], aNI[i]));
                    float hn = fmaf(z, hprev[grp][i] - n, n);
                    hprev[grp][i] = hn;
                    int row = quad * 4 + i;
                    int idx = (row << 6) + ((((col >> 3) ^ (row & 7))) << 3) + (col & 7);
                    wb[idx] = f2bf_h(hn);     // PRE-relu
                }
            }
        }
        __syncthreads();   // slot written at tau is read at tau+1
    }

    // ---- fused epilogue ----
    // E2 waves (8..15) preload Bs2 while E1 computes.
    bf16x8 Bx[2];
    int w2 = wid - 8;
    int grp2 = (w2 >> 2) & 1, jt2 = w2 & 3;
    if (wid >= 8) {
        #pragma unroll
        for (int kc = 0; kc < 2; ++kc)
            Bx[kc] = ld_bfrag(s2sW, 2 * HF, jt2 * 16 + c, kc * 32 + quad * 8);
    }
    if (wid < 8) {   // E1: slow_feat = relu(h3[31]) @ soW + sob  (h3[31]: slot 1)
        int grp1 = wid >> 2, jt1 = wid & 3;
        int col1 = jt1 * 16 + c;
        bf16x8 a0 = ld_afrag(buf[grp1][3][1], c, quad, 0, true);
        bf16x8 a1 = ld_afrag(buf[grp1][3][1], c, quad, 1, true);
        bf16x8 Bso[2];
        #pragma unroll
        for (int kc = 0; kc < 2; ++kc)
            Bso[kc] = ld_bfrag(soW, GH, col1, kc * 32 + quad * 8);
        float bv = sob[col1];
        f32x4 accS = (f32x4){bv, bv, bv, bv};
        accS = MFMA16(a0, Bso[0], accS);
        accS = MFMA16(a1, Bso[1], accS);
        unsigned short* sf = buf[grp1][0][0];    // dead slot: stage slow_feat
        #pragma unroll
        for (int i = 0; i < 4; ++i) {
            int row = quad * 4 + i;
            int idx = (row << 6) + ((((col1 >> 3) ^ (row & 7))) << 3) + (col1 & 7);
            sf[idx] = f2bf_h(accS[i]);
        }
    }
    __syncthreads();
    if (wid >= 8) {   // E2: eps = sf @ s2sW + s2sb -> A_s | g_s
        bf16x8 s0 = ld_afrag(buf[grp2][0][0], c, quad, 0, false);
        bf16x8 s1 = ld_afrag(buf[grp2][0][0], c, quad, 1, false);
        int col2 = jt2 * 16 + c;
        float ev = s2sb[col2];
        f32x4 accE = (f32x4){ev, ev, ev, ev};
        accE = MFMA16(s0, Bx[0], accE);
        accE = MFMA16(s1, Bx[1], accE);
        #pragma unroll
        for (int i = 0; i < 4; ++i) {
            int row = quad * 4 + i;
            float v = accE[i];
            AG[(grp2 * 16 + row) * 65 + col2] = (jt2 < 2) ? sigm(v) : v;
        }
    }
    __syncthreads();
    // E3: fast diagonal SSM + overlap-add. 32 frames x 32 ch on 1024 threads.
    {
        int frame = tid >> 5, fch = tid & 31;
        int q = seqbase + frame;
        if (q < BS) {            // skip duplicated clamp frames (no double-add)
            int b  = (q >= ns) ? 1 : 0;
            int fi = q - b * ns;
            float cA = AG[frame * 65 + fch];
            float cG = AG[frame * 65 + 32 + fch];
            float Gf = finW[fch] * cG;
            float Gb = finb[fch] * cG;
            float cFo = foutW[fch];
            float cfb = foutb[0];
            float h = 0.0f;
            const float* xrow = xs[frame >> 4] + (frame & 15) * 33;
            float* op = out + (size_t)b * T + fi * DS;
            #pragma unroll 1
            for (int t = 0; t < LS; ++t) {
                float xv = xrow[t];
                h = fmaf(cA, h, fmaf(xv, Gf, Gb));
                float s = h * cFo;
                s += __shfl_xor(s, 1);
                s += __shfl_xor(s, 2);
                s += __shfl_xor(s, 4);
                s += __shfl_xor(s, 8);
                s += __shfl_xor(s, 16);
                if (fch == 0) atomicAdd(&op[t], s + cfb);
            }
        }
    }
}

extern "C" void kernel_launch(void* const* d_in, const int* in_sizes, int n_in,
                              void* d_out, int out_size, void* d_ws, size_t ws_size,
                              hipStream_t stream)
{
    (void)n_in; (void)ws_size; (void)d_ws;
    const float* x     = (const float*)d_in[0];
    const float* siW   = (const float*)d_in[1];
    const float* sib   = (const float*)d_in[2];
    const float* Wih   = (const float*)d_in[3];
    const float* Whh   = (const float*)d_in[4];
    const float* bih   = (const float*)d_in[5];
    const float* bhh   = (const float*)d_in[6];
    const float* soW   = (const float*)d_in[7];
    const float* sob   = (const float*)d_in[8];
    const float* s2sW  = (const float*)d_in[9];
    const float* s2sb  = (const float*)d_in[10];
    const float* finW  = (const float*)d_in[11];
    const float* finb  = (const float*)d_in[12];
    const float* foutW = (const float*)d_in[13];
    const float* foutb = (const float*)d_in[14];

    int T  = in_sizes[0] / 2;          // B = 2
    int ns = (T - LS) / DS + 1;        // 3999
    int BS = 2 * ns;                   // 7998

    (void)hipMemsetAsync(d_out, 0, (size_t)out_size * sizeof(float), stream);

    slowfast_fused<<<dim3((BS + 31) / 32), dim3(1024), 0, stream>>>(
        x, siW, sib, Wih, Whh, bih, bhh, soW, sob, s2sW, s2sb,
        finW, finb, foutW, foutb, (float*)d_out, T, ns, BS);
}

// Round 7
// 242.992 us; speedup vs baseline: 1.0510x; 1.0510x over previous
//
#include <hip/hip_runtime.h>
#include <hip/hip_bf16.h>

#define GH 64
#define LS 32
#define HF 32
#define DS 16

typedef short bf16x8 __attribute__((ext_vector_type(8)));
typedef float f32x4 __attribute__((ext_vector_type(4)));

#define MFMA16(a, b, c) __builtin_amdgcn_mfma_f32_16x16x32_bf16(a, b, c, 0, 0, 0)

__device__ __forceinline__ unsigned int f2bf_rne(float f) {
    unsigned int u = __float_as_uint(f);
    return (u + 0x7FFFu + ((u >> 16) & 1u)) >> 16;   // RNE (weights, loaded once)
}
__device__ __forceinline__ unsigned short f2bf_h(float f) {
    return (unsigned short)((__float_as_uint(f) + 0x8000u) >> 16);  // half-up, 2 inst
}
__device__ __forceinline__ unsigned int relu2(unsigned int w) {
    union { unsigned int u; __hip_bfloat162 v; } a, z, r;   // v_pk_max_bf16
    a.u = w; z.u = 0u;
    r.v = __hmax2(a.v, z.v);
    return r.u;
}
// raw-pipe transcendentals: no libm fixup code (|x| here is bounded by gate math)
__device__ __forceinline__ float sigm(float x) {
    float e = __builtin_amdgcn_exp2f(-1.442695041f * x);    // v_mul + v_exp
    return __builtin_amdgcn_rcpf(1.0f + e);                 // v_add + v_rcp
}
__device__ __forceinline__ float tanh_(float x) {
    float e = __builtin_amdgcn_exp2f(2.885390082f * x);
    return fmaf(-2.0f, __builtin_amdgcn_rcpf(e + 1.0f), 1.0f);
}
// pack two f32 -> (bf16(v1)<<16)|bf16(v0) by truncation: single v_perm_b32
__device__ __forceinline__ unsigned int pack_trunc(float v0, float v1) {
    return __builtin_amdgcn_perm(__float_as_uint(v1), __float_as_uint(v0),
                                 0x07060302u);
}

// A-fragment (16x16x32) from one t-slot (16 seq x 64 ch bf16), XOR-swizzled
// 16B blocks: element (seq,ch) at seq*64 + (((ch>>3)^(seq&7))<<3) + (ch&7).
// Conflict-free b128 reads, 2-way-free b16 writes (R4-R6: conflicts ~0).
__device__ __forceinline__ bf16x8 ld_afrag(const unsigned short* slot, int m,
                                           int quad, int half, bool relu) {
    int b   = half * 4 + quad;
    int idx = (m << 6) + ((b ^ (m & 7)) << 3);
    uint4 d = *reinterpret_cast<const uint4*>(slot + idx);
    if (relu) { d.x = relu2(d.x); d.y = relu2(d.y); d.z = relu2(d.z); d.w = relu2(d.w); }
    union { uint4 u; bf16x8 v; } cv; cv.u = d;
    return cv.v;
}
// B-fragment: lane holds B[k=kc*32+quad*8+j][col]; fp32 -> bf16 RNE (once).
__device__ __forceinline__ bf16x8 ld_bfrag(const float* __restrict__ W, int ldw,
                                           int col, int k0) {
    bf16x8 f;
    #pragma unroll
    for (int j = 0; j < 8; ++j)
        f[j] = (short)f2bf_rne(W[(k0 + j) * ldw + col]);
    return f;
}

// Block = 4 waves x 64 (wave jt owns gate-column tile [jt*16,jt*16+16)).
// Block owns 16 sequences: 4 GRU layers run sequentially, in-place on one
// 64 KB hseq buffer (pre-relu h; relu applied on input-frag load).
// ONE barrier/step: input A-frags for t+1 are prefetched before the barrier
// (hseq[t+1] is not written until step t+1; at t=31 slot 0 already holds this
// layer's t=0 output = next layer's input). Then fused slow_out/s2s epilogue
// and fast diagonal SSM with overlap-add atomics, all in one dispatch.
__global__ __launch_bounds__(256, 2) void slowfast_fused(
    const float* __restrict__ x,
    const float* __restrict__ siW,  const float* __restrict__ sib,
    const float* __restrict__ Wih,  const float* __restrict__ Whh,
    const float* __restrict__ bih,  const float* __restrict__ bhh,
    const float* __restrict__ soW,  const float* __restrict__ sob,
    const float* __restrict__ s2sW, const float* __restrict__ s2sb,
    const float* __restrict__ finW, const float* __restrict__ finb,
    const float* __restrict__ foutW, const float* __restrict__ foutb,
    float* __restrict__ out,
    int T, int ns, int BS)
{
    __shared__ __align__(16) unsigned short hseq[LS * 16 * 64];  // 64 KB
    __shared__ float xs[16 * 33];    // x windows for the SSM (pad-33)
    __shared__ float AG[16 * 65];    // A_s | g_s staging (pad-65)

    const int tid  = threadIdx.x;
    const int lane = tid & 63;
    const int jt   = tid >> 6;
    const int c    = lane & 15;
    const int quad = lane >> 4;
    const int col  = jt * 16 + c;
    const int seqbase = blockIdx.x * 16;

    // ---- stage x windows + layer-0 pre-activations (pre-relu, trunc pack) ----
    for (int p = tid; p < 512; p += 256) {           // p = seq*32 + t
        int seq = p >> 5, t = p & 31;
        int q = seqbase + seq; if (q > BS - 1) q = BS - 1;
        int b  = (q >= ns) ? 1 : 0;
        int si = q - b * ns;
        float xv = x[b * T + si * DS + t];
        xs[seq * 33 + t] = xv;
        int base = (t << 10) + (seq << 6);
        int sw   = seq & 7;
        #pragma unroll
        for (int dp = 0; dp < 32; ++dp) {
            int ch = dp << 1;
            float v0 = fmaf(xv, siW[ch],     sib[ch]);      // uniform -> s_load
            float v1 = fmaf(xv, siW[ch + 1], sib[ch + 1]);
            int idx = base + ((((ch >> 3) ^ sw)) << 3) + (ch & 7);
            *reinterpret_cast<unsigned int*>(&hseq[idx]) = pack_trunc(v0, v1);
        }
    }

    // hoisted write indices for this lane's 4 (row,col) gate elements
    int wIdx[4];
    #pragma unroll
    for (int i = 0; i < 4; ++i) {
        int row = quad * 4 + i;
        wIdx[i] = (row << 6) + ((((col >> 3) ^ (row & 7))) << 3) + (col & 7);
    }

    __syncthreads();

    // initial input-frag prefetch (layer 0 input at t=0)
    bf16x8 a0 = ld_afrag(hseq, c, quad, 0, true);
    bf16x8 a1 = ld_afrag(hseq, c, quad, 1, true);

    for (int l = 0; l < 4; ++l) {
        const float* Wi = Wih + (size_t)l * GH * 192;
        const float* Wh = Whh + (size_t)l * GH * 192;
        bf16x8 BiR[2], BiZ[2], BiN[2], BhR[2], BhZ[2], BhN[2];
        #pragma unroll
        for (int kc = 0; kc < 2; ++kc) {
            int k0 = kc * 32 + quad * 8;
            BiR[kc] = ld_bfrag(Wi, 192,       col, k0);
            BiZ[kc] = ld_bfrag(Wi, 192,  64 + col, k0);
            BiN[kc] = ld_bfrag(Wi, 192, 128 + col, k0);
            BhR[kc] = ld_bfrag(Wh, 192,       col, k0);
            BhZ[kc] = ld_bfrag(Wh, 192,  64 + col, k0);
            BhN[kc] = ld_bfrag(Wh, 192, 128 + col, k0);
        }
        float bRs  = bih[l * 192 + col]      + bhh[l * 192 + col];
        float bZs  = bih[l * 192 + 64 + col] + bhh[l * 192 + 64 + col];
        float bNIs = bih[l * 192 + 128 + col];   // n-gate ih/hh separate:
        float bNHs = bhh[l * 192 + 128 + col];   // tanh(xg_n + r*hg_n)
        const f32x4 vbR  = (f32x4){bRs,  bRs,  bRs,  bRs};   // resident C-operands
        const f32x4 vbZ  = (f32x4){bZs,  bZs,  bZs,  bZs};
        const f32x4 vbNI = (f32x4){bNIs, bNIs, bNIs, bNIs};
        const f32x4 vbNH = (f32x4){bNHs, bNHs, bNHs, bNHs};

        float hprev[4] = {0.0f, 0.0f, 0.0f, 0.0f};

        #pragma unroll 1
        for (int t = 0; t < LS; ++t) {
            f32x4 aR  = MFMA16(a0, BiR[0], vbR);    // C = bias (no init movs)
            f32x4 aZ  = MFMA16(a0, BiZ[0], vbZ);
            f32x4 aNI = MFMA16(a0, BiN[0], vbNI);
            aR  = MFMA16(a1, BiR[1], aR);
            aZ  = MFMA16(a1, BiZ[1], aZ);
            aNI = MFMA16(a1, BiN[1], aNI);
            f32x4 aNH = vbNH;
            if (t > 0) {
                const unsigned short* hb = hseq + ((t - 1) << 10);
                bf16x8 h0 = ld_afrag(hb, c, quad, 0, false);   // pre-relu recurrent
                bf16x8 h1 = ld_afrag(hb, c, quad, 1, false);
                aR  = MFMA16(h0, BhR[0], aR);
                aZ  = MFMA16(h0, BhZ[0], aZ);
                aNH = MFMA16(h0, BhN[0], aNH);
                aR  = MFMA16(h1, BhR[1], aR);
                aZ  = MFMA16(h1, BhZ[1], aZ);
                aNH = MFMA16(h1, BhN[1], aNH);
            }
            unsigned short* wb = hseq + (t << 10);
            #pragma unroll
            for (int i = 0; i < 4; ++i) {
                float r  = sigm(aR[i]);
                float z  = sigm(aZ[i]);
                float n  = tanh_(fmaf(r, aNH[i], aNI[i]));
                float hn = fmaf(z, hprev[i] - n, n);
                hprev[i] = hn;
                wb[wIdx[i]] = f2bf_h(hn);            // store PRE-relu
            }
            // prefetch next input frags: hseq[(t+1)&31] is untouched until
            // step t+1 (at t=31: slot 0 = this layer's t=0 out = next input)
            const unsigned short* nb = hseq + (((t + 1) & 31) << 10);
            a0 = ld_afrag(nb, c, quad, 0, true);
            a1 = ld_afrag(nb, c, quad, 1, true);
            __syncthreads();   // single fence: write(t) vs reads, prefetch vs write(t+1)
        }
    }

    // ---- fused epilogue ----
    {   // E1: slow_feat = relu(h3[31]) @ soW + sob  -> stage bf16 in slot 0
        bf16x8 e0 = ld_afrag(hseq + (31 << 10), c, quad, 0, true);
        bf16x8 e1 = ld_afrag(hseq + (31 << 10), c, quad, 1, true);
        bf16x8 Bso[2], Bs2[2];
        #pragma unroll
        for (int kc = 0; kc < 2; ++kc) {
            int k0 = kc * 32 + quad * 8;
            Bso[kc] = ld_bfrag(soW,  GH,     col, k0);
            Bs2[kc] = ld_bfrag(s2sW, 2 * HF, col, k0);
        }
        float sb = sob[col];
        f32x4 accS = (f32x4){sb, sb, sb, sb};
        accS = MFMA16(e0, Bso[0], accS);
        accS = MFMA16(e1, Bso[1], accS);
        #pragma unroll
        for (int i = 0; i < 4; ++i)
            hseq[wIdx[i]] = f2bf_h(accS[i]);         // slot 0 is dead: stage sf
        __syncthreads();
        // E2: eps = sf @ s2sW + s2sb -> A_s | g_s
        bf16x8 s0 = ld_afrag(hseq, c, quad, 0, false);
        bf16x8 s1 = ld_afrag(hseq, c, quad, 1, false);
        float eb = s2sb[col];
        f32x4 accE = (f32x4){eb, eb, eb, eb};
        accE = MFMA16(s0, Bs2[0], accE);
        accE = MFMA16(s1, Bs2[1], accE);
        #pragma unroll
        for (int i = 0; i < 4; ++i) {
            int row = quad * 4 + i;
            float v = accE[i];
            AG[row * 65 + col] = (jt < 2) ? sigm(v) : v;
        }
    }
    __syncthreads();
    // E3: fast diagonal SSM + overlap-add. 16 frames x 32 ch over 2 passes.
    {
        int fch = tid & 31;
        float Gfw = finW[fch], Gbw = finb[fch], cFo = foutW[fch], cfb = foutb[0];
        #pragma unroll
        for (int half = 0; half < 2; ++half) {
            int frame = half * 8 + (tid >> 5);
            int q = seqbase + frame;
            if (q < BS) {        // skip duplicated clamp frames (no double-add)
                int b  = (q >= ns) ? 1 : 0;
                int fi = q - b * ns;
                float cA = AG[frame * 65 + fch];
                float cG = AG[frame * 65 + 32 + fch];
                float Gf = Gfw * cG;
                float Gb = Gbw * cG;
                float h = 0.0f;
                const float* xrow = xs + frame * 33;
                float* op = out + (size_t)b * T + fi * DS;
                #pragma unroll 1
                for (int t = 0; t < LS; ++t) {
                    h = fmaf(cA, h, fmaf(xrow[t], Gf, Gb));
                    float s = h * cFo;
                    s += __shfl_xor(s, 1);
                    s += __shfl_xor(s, 2);
                    s += __shfl_xor(s, 4);
                    s += __shfl_xor(s, 8);
                    s += __shfl_xor(s, 16);
                    if (fch == 0) atomicAdd(&op[t], s + cfb);
                }
            }
        }
    }
}

extern "C" void kernel_launch(void* const* d_in, const int* in_sizes, int n_in,
                              void* d_out, int out_size, void* d_ws, size_t ws_size,
                              hipStream_t stream)
{
    (void)n_in; (void)ws_size; (void)d_ws;
    const float* x     = (const float*)d_in[0];
    const float* siW   = (const float*)d_in[1];
    const float* sib   = (const float*)d_in[2];
    const float* Wih   = (const float*)d_in[3];
    const float* Whh   = (const float*)d_in[4];
    const float* bih   = (const float*)d_in[5];
    const float* bhh   = (const float*)d_in[6];
    const float* soW   = (const float*)d_in[7];
    const float* sob   = (const float*)d_in[8];
    const float* s2sW  = (const float*)d_in[9];
    const float* s2sb  = (const float*)d_in[10];
    const float* finW  = (const float*)d_in[11];
    const float* finb  = (const float*)d_in[12];
    const float* foutW = (const float*)d_in[13];
    const float* foutb = (const float*)d_in[14];

    int T  = in_sizes[0] / 2;          // B = 2
    int ns = (T - LS) / DS + 1;        // 3999
    int BS = 2 * ns;                   // 7998

    (void)hipMemsetAsync(d_out, 0, (size_t)out_size * sizeof(float), stream);

    slowfast_fused<<<dim3((BS + 15) / 16), dim3(256), 0, stream>>>(
        x, siW, sib, Wih, Whh, bih, bhh, soW, sob, s2sW, s2sb,
        finW, finb, foutW, foutb, (float*)d_out, T, ns, BS);
}

// Round 8
// 182.444 us; speedup vs baseline: 1.3997x; 1.3319x over previous
//
#include <hip/hip_runtime.h>

#define GH 64
#define LS 32
#define HF 32
#define DS 16

typedef short bf16x8 __attribute__((ext_vector_type(8)));
typedef float f32x4 __attribute__((ext_vector_type(4)));

#define MFMA16(a, b, c) __builtin_amdgcn_mfma_f32_16x16x32_bf16(a, b, c, 0, 0, 0)

__device__ __forceinline__ unsigned int f2bf_rne(float f) {
    unsigned int u = __float_as_uint(f);
    return (u + 0x7FFFu + ((u >> 16) & 1u)) >> 16;   // RNE (prep kernel only)
}
__device__ __forceinline__ unsigned short f2bf_h(float f) {
    return (unsigned short)((__float_as_uint(f) + 0x8000u) >> 16);  // half-up
}
// raw-pipe transcendentals (gate args are bounded; no libm fixups)
__device__ __forceinline__ float sigm(float x) {
    float e = __builtin_amdgcn_exp2f(-1.442695041f * x);
    return __builtin_amdgcn_rcpf(1.0f + e);
}
__device__ __forceinline__ float tanh_(float x) {
    float e = __builtin_amdgcn_exp2f(2.885390082f * x);
    return fmaf(-2.0f, __builtin_amdgcn_rcpf(e + 1.0f), 1.0f);
}
__device__ __forceinline__ unsigned int pack_trunc(float v0, float v1) {
    return __builtin_amdgcn_perm(__float_as_uint(v1), __float_as_uint(v0),
                                 0x07060302u);   // (bf16(v1)<<16)|bf16(v0)
}
__device__ __forceinline__ bf16x8 as_frag(uint4 u) {
    union { uint4 a; bf16x8 b; } cv; cv.a = u; return cv.b;
}

// A-fragment from one 16x64 bf16 slot, XOR-swizzled 16B blocks:
// (seq,ch) at seq*64 + (((ch>>3)^(seq&7))<<3) + (ch&7). No relu anywhere.
__device__ __forceinline__ bf16x8 ld_afrag(const unsigned short* slot, int m,
                                           int quad, int half) {
    int b   = half * 4 + quad;
    int idx = (m << 6) + ((b ^ (m & 7)) << 3);
    return as_frag(*reinterpret_cast<const uint4*>(slot + idx));
}

// ---- prep: fp32 weights -> bf16 MFMA B-fragments, fragment-ordered in ws ----
// Element idx = rest*1024 + kc*512 + lane*8 + j.
// GRU (rest<96): rest=(l*6+mat)*4+jt, mat 0..2 = Wih r/z/n, 3..5 = Whh r/z/n.
// Epi (rest=96..103): rest=96+m2*4+jt, m2: 0=soW, 1=s2sW.
__global__ __launch_bounds__(256) void prep_weights(
    const float* __restrict__ Wih, const float* __restrict__ Whh,
    const float* __restrict__ soW, const float* __restrict__ s2sW,
    unsigned short* __restrict__ wsW)
{
    int idx = blockIdx.x * 256 + threadIdx.x;
    if (idx >= 104 * 1024) return;
    int j = idx & 7, lane = (idx >> 3) & 63, kc = (idx >> 9) & 1, rest = idx >> 10;
    int k = kc * 32 + ((lane >> 4) << 3) + j;
    int c = lane & 15;
    float v;
    if (rest < 96) {
        int jt = rest & 3, mt = rest >> 2;
        int l = mt / 6, mat = mt - l * 6;
        int col = jt * 16 + c;
        const float* W = (mat < 3) ? Wih + (size_t)l * GH * 192
                                   : Whh + (size_t)l * GH * 192;
        int m3 = (mat < 3) ? mat : mat - 3;
        v = W[k * 192 + m3 * 64 + col];
    } else {
        int r2 = rest - 96;
        int jt = r2 & 3, m2 = r2 >> 2;
        int col = jt * 16 + c;
        v = (m2 ? s2sW : soW)[k * 64 + col];
    }
    wsW[idx] = (unsigned short)f2bf_rne(v);
}

// Block = 4 waves x 64 (wave jt owns gate cols [jt*16,jt*16+16)); 16 seqs.
// hseq: RELU'D h (next-layer input), in-place across layers, 64 KB.
// hrec: PRE-relu h, 2-slot ping-pong (recurrence needs only t-1), 4 KB.
// One barrier/step; a(t+1) prefetched pre-barrier. Weights from prepped ws
// (12 coalesced dwordx4 per lane per layer). Fused epilogue + fast SSM.
__global__ __launch_bounds__(256, 2) void slowfast_fused(
    const float* __restrict__ x,
    const float* __restrict__ siW,  const float* __restrict__ sib,
    const float* __restrict__ bih,  const float* __restrict__ bhh,
    const float* __restrict__ sob,  const float* __restrict__ s2sb,
    const float* __restrict__ finW, const float* __restrict__ finb,
    const float* __restrict__ foutW, const float* __restrict__ foutb,
    const unsigned short* __restrict__ wsW,
    float* __restrict__ out,
    int T, int ns, int BS)
{
    __shared__ __align__(16) unsigned short hseq[LS * 16 * 64];  // 64 KB
    __shared__ __align__(16) unsigned short hrec[2 * 16 * 64];   // 4 KB
    __shared__ float xs[16 * 33];    // x windows (pad-33)
    __shared__ float AG[16 * 65];    // A_s | g_s staging (pad-65)

    const int tid  = threadIdx.x;
    const int lane = tid & 63;
    const int jt   = tid >> 6;
    const int c    = lane & 15;
    const int quad = lane >> 4;
    const int col  = jt * 16 + c;
    const int seqbase = blockIdx.x * 16;
    const uint4* wf = reinterpret_cast<const uint4*>(wsW);

    // ---- stage x windows ----
    for (int p = tid; p < 512; p += 256) {           // p = seq*32 + t
        int seq = p >> 5, t = p & 31;
        int q = seqbase + seq; if (q > BS - 1) q = BS - 1;
        int b  = (q >= ns) ? 1 : 0;
        int si = q - b * ns;
        xs[seq * 33 + t] = x[b * T + si * DS + t];
    }
    __syncthreads();

    // ---- layer-0 inputs: relu(x*siW+sib), packed dword writes, conflict-free
    {
        int chp = tid & 31;          // channel pair id
        int grp = tid >> 5;          // 8 groups over 512 (seq,t) pairs
        int ch  = chp << 1;
        float w0 = siW[ch], w1 = siW[ch + 1];
        float b0 = sib[ch], b1 = sib[ch + 1];
        #pragma unroll 4
        for (int it = 0; it < 64; ++it) {
            int p = grp + (it << 3);
            int s = p >> 5, t = p & 31;
            float xv = xs[s * 33 + t];
            float v0 = fmaxf(fmaf(xv, w0, b0), 0.0f);
            float v1 = fmaxf(fmaf(xv, w1, b1), 0.0f);
            int idx = (t << 10) + (s << 6) + ((((ch >> 3) ^ (s & 7))) << 3) + (ch & 7);
            *reinterpret_cast<unsigned int*>(&hseq[idx]) = pack_trunc(v0, v1);
        }
    }

    // hoisted write indices for this lane's 4 (row,col) gate elements
    int wIdx[4];
    #pragma unroll
    for (int i = 0; i < 4; ++i) {
        int row = quad * 4 + i;
        wIdx[i] = (row << 6) + ((((col >> 3) ^ (row & 7))) << 3) + (col & 7);
    }

    __syncthreads();

    bf16x8 a0 = ld_afrag(hseq, c, quad, 0);   // layer-0 input, t=0 (relu'd)
    bf16x8 a1 = ld_afrag(hseq, c, quad, 1);

    for (int l = 0; l < 4; ++l) {
        // 12 coalesced 16B fragment loads from prepped ws
        bf16x8 BiR[2], BiZ[2], BiN[2], BhR[2], BhZ[2], BhN[2];
        #pragma unroll
        for (int kc = 0; kc < 2; ++kc) {
            int base = (l * 6 * 4 + jt) * 128 + kc * 64 + lane;  // mat stride 512
            BiR[kc] = as_frag(wf[base]);
            BiZ[kc] = as_frag(wf[base + 512]);
            BiN[kc] = as_frag(wf[base + 1024]);
            BhR[kc] = as_frag(wf[base + 1536]);
            BhZ[kc] = as_frag(wf[base + 2048]);
            BhN[kc] = as_frag(wf[base + 2560]);
        }
        float bRs  = bih[l * 192 + col]      + bhh[l * 192 + col];
        float bZs  = bih[l * 192 + 64 + col] + bhh[l * 192 + 64 + col];
        float bNIs = bih[l * 192 + 128 + col];   // n-gate ih/hh separate:
        float bNHs = bhh[l * 192 + 128 + col];   // tanh(xg_n + r*hg_n)
        const f32x4 vbR  = (f32x4){bRs,  bRs,  bRs,  bRs};
        const f32x4 vbZ  = (f32x4){bZs,  bZs,  bZs,  bZs};
        const f32x4 vbNI = (f32x4){bNIs, bNIs, bNIs, bNIs};
        const f32x4 vbNH = (f32x4){bNHs, bNHs, bNHs, bNHs};

        float hprev[4] = {0.0f, 0.0f, 0.0f, 0.0f};

        #pragma unroll 1
        for (int t = 0; t < LS; ++t) {
            f32x4 aR  = MFMA16(a0, BiR[0], vbR);
            f32x4 aZ  = MFMA16(a0, BiZ[0], vbZ);
            f32x4 aNI = MFMA16(a0, BiN[0], vbNI);
            aR  = MFMA16(a1, BiR[1], aR);
            aZ  = MFMA16(a1, BiZ[1], aZ);
            aNI = MFMA16(a1, BiN[1], aNI);
            f32x4 aNH = vbNH;
            if (t > 0) {
                const unsigned short* hb = hrec + (((t - 1) & 1) << 10);
                bf16x8 h0 = ld_afrag(hb, c, quad, 0);   // pre-relu recurrent
                bf16x8 h1 = ld_afrag(hb, c, quad, 1);
                aR  = MFMA16(h0, BhR[0], aR);
                aZ  = MFMA16(h0, BhZ[0], aZ);
                aNH = MFMA16(h0, BhN[0], aNH);
                aR  = MFMA16(h1, BhR[1], aR);
                aZ  = MFMA16(h1, BhZ[1], aZ);
                aNH = MFMA16(h1, BhN[1], aNH);
            }
            unsigned short* wb = hseq + (t << 10);
            unsigned short* wr = hrec + ((t & 1) << 10);
            #pragma unroll
            for (int i = 0; i < 4; ++i) {
                float r  = sigm(aR[i]);
                float z  = sigm(aZ[i]);
                float n  = tanh_(fmaf(r, aNH[i], aNI[i]));
                float hn = fmaf(z, hprev[i] - n, n);
                hprev[i] = hn;
                wr[wIdx[i]] = f2bf_h(hn);                   // pre-relu (recurrence)
                wb[wIdx[i]] = f2bf_h(fmaxf(hn, 0.0f));      // relu'd (next layer)
            }
            // prefetch next input: slot t+1 untouched this step; at t=31 slot 0
            // already holds this layer's relu'd t=0 output = next layer's input
            const unsigned short* nb = hseq + (((t + 1) & 31) << 10);
            a0 = ld_afrag(nb, c, quad, 0);
            a1 = ld_afrag(nb, c, quad, 1);
            __syncthreads();
        }
    }

    // ---- fused epilogue ----
    {   // E1: slow_feat = hseq[31] (already relu'd) @ soW + sob -> stage slot 0
        bf16x8 e0 = ld_afrag(hseq + (31 << 10), c, quad, 0);
        bf16x8 e1 = ld_afrag(hseq + (31 << 10), c, quad, 1);
        bf16x8 Bso[2], Bs2[2];
        #pragma unroll
        for (int kc = 0; kc < 2; ++kc) {
            Bso[kc] = as_frag(wf[(96 + jt)  * 128 + kc * 64 + lane]);
            Bs2[kc] = as_frag(wf[(100 + jt) * 128 + kc * 64 + lane]);
        }
        float sb = sob[col];
        f32x4 accS = (f32x4){sb, sb, sb, sb};
        accS = MFMA16(e0, Bso[0], accS);
        accS = MFMA16(e1, Bso[1], accS);
        #pragma unroll
        for (int i = 0; i < 4; ++i)
            hseq[wIdx[i]] = f2bf_h(accS[i]);     // slot 0 dead: stage slow_feat
        __syncthreads();
        // E2: eps = sf @ s2sW + s2sb -> A_s | g_s
        bf16x8 s0 = ld_afrag(hseq, c, quad, 0);
        bf16x8 s1 = ld_afrag(hseq, c, quad, 1);
        float eb = s2sb[col];
        f32x4 accE = (f32x4){eb, eb, eb, eb};
        accE = MFMA16(s0, Bs2[0], accE);
        accE = MFMA16(s1, Bs2[1], accE);
        #pragma unroll
        for (int i = 0; i < 4; ++i) {
            int row = quad * 4 + i;
            float v = accE[i];
            AG[row * 65 + col] = (jt < 2) ? sigm(v) : v;
        }
    }
    __syncthreads();
    // E3: fast diagonal SSM + overlap-add (16 frames x 32 ch, 2 passes)
    {
        int fch = tid & 31;
        float Gfw = finW[fch], Gbw = finb[fch], cFo = foutW[fch], cfb = foutb[0];
        #pragma unroll
        for (int half = 0; half < 2; ++half) {
            int frame = half * 8 + (tid >> 5);
            int q = seqbase + frame;
            if (q < BS) {        // skip duplicated clamp frames (no double-add)
                int b  = (q >= ns) ? 1 : 0;
                int fi = q - b * ns;
                float cA = AG[frame * 65 + fch];
                float cG = AG[frame * 65 + 32 + fch];
                float Gf = Gfw * cG;
                float Gb = Gbw * cG;
                float h = 0.0f;
                const float* xrow = xs + frame * 33;
                float* op = out + (size_t)b * T + fi * DS;
                #pragma unroll 1
                for (int t = 0; t < LS; ++t) {
                    h = fmaf(cA, h, fmaf(xrow[t], Gf, Gb));
                    float s = h * cFo;
                    s += __shfl_xor(s, 1);
                    s += __shfl_xor(s, 2);
                    s += __shfl_xor(s, 4);
                    s += __shfl_xor(s, 8);
                    s += __shfl_xor(s, 16);
                    if (fch == 0) atomicAdd(&op[t], s + cfb);
                }
            }
        }
    }
}

extern "C" void kernel_launch(void* const* d_in, const int* in_sizes, int n_in,
                              void* d_out, int out_size, void* d_ws, size_t ws_size,
                              hipStream_t stream)
{
    (void)n_in; (void)ws_size;
    const float* x     = (const float*)d_in[0];
    const float* siW   = (const float*)d_in[1];
    const float* sib   = (const float*)d_in[2];
    const float* Wih   = (const float*)d_in[3];
    const float* Whh   = (const float*)d_in[4];
    const float* bih   = (const float*)d_in[5];
    const float* bhh   = (const float*)d_in[6];
    const float* soW   = (const float*)d_in[7];
    const float* sob   = (const float*)d_in[8];
    const float* s2sW  = (const float*)d_in[9];
    const float* s2sb  = (const float*)d_in[10];
    const float* finW  = (const float*)d_in[11];
    const float* finb  = (const float*)d_in[12];
    const float* foutW = (const float*)d_in[13];
    const float* foutb = (const float*)d_in[14];

    int T  = in_sizes[0] / 2;          // B = 2
    int ns = (T - LS) / DS + 1;        // 3999
    int BS = 2 * ns;                   // 7998

    unsigned short* wsW = (unsigned short*)d_ws;   // 104*1024 bf16 = 208 KB

    (void)hipMemsetAsync(d_out, 0, (size_t)out_size * sizeof(float), stream);

    prep_weights<<<dim3(416), dim3(256), 0, stream>>>(Wih, Whh, soW, s2sW, wsW);

    slowfast_fused<<<dim3((BS + 15) / 16), dim3(256), 0, stream>>>(
        x, siW, sib, bih, bhh, sob, s2sb, finW, finb, foutW, foutb,
        wsW, (float*)d_out, T, ns, BS);
}

// Round 9
// 171.569 us; speedup vs baseline: 1.4885x; 1.0634x over previous
//
#include <hip/hip_runtime.h>

#define GH 64
#define LS 32
#define HF 32
#define DS 16

// transcendental folding constants (exact fp32 rescale of weights at prep)
#define NLOG2E -1.4426950408889634f   // r,z columns:  sigm(x)=rcp(1+exp2(-log2e*x))
#define P2LOG2E 2.8853900817779268f   // n columns:    tanh(x)=1-2*rcp(exp2(2log2e*x)+1)

typedef short bf16x8 __attribute__((ext_vector_type(8)));
typedef float f32x4 __attribute__((ext_vector_type(4)));

#define MFMA16(a, b, c) __builtin_amdgcn_mfma_f32_16x16x32_bf16(a, b, c, 0, 0, 0)

__device__ __forceinline__ unsigned int f2bf_rne(float f) {
    unsigned int u = __float_as_uint(f);
    return (u + 0x7FFFu + ((u >> 16) & 1u)) >> 16;   // RNE (prep kernel only)
}
__device__ __forceinline__ unsigned short f2bf_h(float f) {
    return (unsigned short)((__float_as_uint(f) + 0x8000u) >> 16);  // half-up
}
__device__ __forceinline__ unsigned int pack_trunc(float v0, float v1) {
    return __builtin_amdgcn_perm(__float_as_uint(v1), __float_as_uint(v0),
                                 0x07060302u);   // (bf16(v1)<<16)|bf16(v0)
}
__device__ __forceinline__ bf16x8 as_frag(uint4 u) {
    union { uint4 a; bf16x8 b; } cv; cv.a = u; return cv.b;
}

// A-fragment from one 16x64 bf16 slot, XOR-swizzled 16B blocks:
// (seq,ch) at seq*64 + (((ch>>3)^(seq&7))<<3) + (ch&7).
__device__ __forceinline__ bf16x8 ld_afrag(const unsigned short* slot, int m,
                                           int quad, int half) {
    int b   = half * 4 + quad;
    int idx = (m << 6) + ((b ^ (m & 7)) << 3);
    return as_frag(*reinterpret_cast<const uint4*>(slot + idx));
}

// ---- prep: fp32 weights -> bf16 MFMA B-fragments, fragment-ordered, with
// the transcendental scale constants FOLDED IN (r,z: -log2e; n: +2log2e;
// s2sW A-half: -log2e). Element idx = rest*1024 + kc*512 + lane*8 + j.
// GRU (rest<96): rest=(l*6+mat)*4+jt, mat 0..2 = Wih r/z/n, 3..5 = Whh r/z/n.
// Epi (rest=96..103): rest=96+m2*4+jt, m2: 0=soW (unscaled), 1=s2sW.
__global__ __launch_bounds__(256) void prep_weights(
    const float* __restrict__ Wih, const float* __restrict__ Whh,
    const float* __restrict__ soW, const float* __restrict__ s2sW,
    unsigned short* __restrict__ wsW)
{
    int idx = blockIdx.x * 256 + threadIdx.x;
    if (idx >= 104 * 1024) return;
    int j = idx & 7, lane = (idx >> 3) & 63, kc = (idx >> 9) & 1, rest = idx >> 10;
    int k = kc * 32 + ((lane >> 4) << 3) + j;
    int c = lane & 15;
    float v;
    if (rest < 96) {
        int jt = rest & 3, mt = rest >> 2;
        int l = mt / 6, mat = mt - l * 6;
        int col = jt * 16 + c;
        const float* W = (mat < 3) ? Wih + (size_t)l * GH * 192
                                   : Whh + (size_t)l * GH * 192;
        int m3 = (mat < 3) ? mat : mat - 3;
        v = W[k * 192 + m3 * 64 + col];
        v *= (m3 == 2) ? P2LOG2E : NLOG2E;       // fold trans scale
    } else {
        int r2 = rest - 96;
        int jt = r2 & 3, m2 = r2 >> 2;
        int col = jt * 16 + c;
        v = (m2 ? s2sW : soW)[k * 64 + col];
        if (m2 && jt < 2) v *= NLOG2E;           // A_s sigmoid half
    }
    wsW[idx] = (unsigned short)f2bf_rne(v);
}

// Block = 4 waves x 64 (wave jt owns gate cols [jt*16,jt*16+16)); 16 seqs.
// hseq: RELU'D h (next-layer input), in-place across layers, 64 KB.
// hrec: PRE-relu h, 2-slot ping-pong (recurrence needs only t-1), 4 KB.
// One barrier/step; a(t+1) prefetched pre-barrier; t-loop unroll-2 makes the
// ping-pong parity static. Weights pre-scaled so exp2 applies directly to
// the MFMA accumulator (no per-element muls). Fused epilogue + fast SSM.
__global__ __launch_bounds__(256, 2) void slowfast_fused(
    const float* __restrict__ x,
    const float* __restrict__ siW,  const float* __restrict__ sib,
    const float* __restrict__ bih,  const float* __restrict__ bhh,
    const float* __restrict__ sob,  const float* __restrict__ s2sb,
    const float* __restrict__ finW, const float* __restrict__ finb,
    const float* __restrict__ foutW, const float* __restrict__ foutb,
    const unsigned short* __restrict__ wsW,
    float* __restrict__ out,
    int T, int ns, int BS)
{
    __shared__ __align__(16) unsigned short hseq[LS * 16 * 64];  // 64 KB
    __shared__ __align__(16) unsigned short hrec[2 * 16 * 64];   // 4 KB
    __shared__ float xs[16 * 33];    // x windows (pad-33)
    __shared__ float AG[16 * 65];    // A_s | g_s staging (pad-65)

    const int tid  = threadIdx.x;
    const int lane = tid & 63;
    const int jt   = tid >> 6;
    const int c    = lane & 15;
    const int quad = lane >> 4;
    const int col  = jt * 16 + c;
    const int seqbase = blockIdx.x * 16;
    const uint4* wf = reinterpret_cast<const uint4*>(wsW);

    // ---- stage x windows ----
    for (int p = tid; p < 512; p += 256) {           // p = seq*32 + t
        int seq = p >> 5, t = p & 31;
        int q = seqbase + seq; if (q > BS - 1) q = BS - 1;
        int b  = (q >= ns) ? 1 : 0;
        int si = q - b * ns;
        xs[seq * 33 + t] = x[b * T + si * DS + t];
    }
    __syncthreads();

    // ---- layer-0 inputs: relu(x*siW+sib), packed dword writes, conflict-free
    {
        int chp = tid & 31;          // channel pair id
        int grp = tid >> 5;          // 8 groups over 512 (seq,t) pairs
        int ch  = chp << 1;
        float w0 = siW[ch], w1 = siW[ch + 1];
        float b0 = sib[ch], b1 = sib[ch + 1];
        #pragma unroll 4
        for (int it = 0; it < 64; ++it) {
            int p = grp + (it << 3);
            int s = p >> 5, t = p & 31;
            float xv = xs[s * 33 + t];
            float v0 = fmaxf(fmaf(xv, w0, b0), 0.0f);
            float v1 = fmaxf(fmaf(xv, w1, b1), 0.0f);
            int idx = (t << 10) + (s << 6) + ((((ch >> 3) ^ (s & 7))) << 3) + (ch & 7);
            *reinterpret_cast<unsigned int*>(&hseq[idx]) = pack_trunc(v0, v1);
        }
    }

    // hoisted write indices for this lane's 4 (row,col) gate elements
    int wIdx[4];
    #pragma unroll
    for (int i = 0; i < 4; ++i) {
        int row = quad * 4 + i;
        wIdx[i] = (row << 6) + ((((col >> 3) ^ (row & 7))) << 3) + (col & 7);
    }

    __syncthreads();

    bf16x8 a0 = ld_afrag(hseq, c, quad, 0);   // layer-0 input, t=0 (relu'd)
    bf16x8 a1 = ld_afrag(hseq, c, quad, 1);

    for (int l = 0; l < 4; ++l) {
        // 12 coalesced 16B fragment loads from prepped (pre-scaled) ws
        bf16x8 BiR[2], BiZ[2], BiN[2], BhR[2], BhZ[2], BhN[2];
        #pragma unroll
        for (int kc = 0; kc < 2; ++kc) {
            int base = (l * 6 * 4 + jt) * 128 + kc * 64 + lane;  // mat stride 512
            BiR[kc] = as_frag(wf[base]);
            BiZ[kc] = as_frag(wf[base + 512]);
            BiN[kc] = as_frag(wf[base + 1024]);
            BhR[kc] = as_frag(wf[base + 1536]);
            BhZ[kc] = as_frag(wf[base + 2048]);
            BhN[kc] = as_frag(wf[base + 2560]);
        }
        // biases carry the same folded scales
        float bRs  = NLOG2E  * (bih[l * 192 + col]      + bhh[l * 192 + col]);
        float bZs  = NLOG2E  * (bih[l * 192 + 64 + col] + bhh[l * 192 + 64 + col]);
        float bNIs = P2LOG2E * bih[l * 192 + 128 + col];  // n-gate ih/hh separate:
        float bNHs = P2LOG2E * bhh[l * 192 + 128 + col];  // tanh(xg_n + r*hg_n)
        const f32x4 vbR  = (f32x4){bRs,  bRs,  bRs,  bRs};
        const f32x4 vbZ  = (f32x4){bZs,  bZs,  bZs,  bZs};
        const f32x4 vbNI = (f32x4){bNIs, bNIs, bNIs, bNIs};
        const f32x4 vbNH = (f32x4){bNHs, bNHs, bNHs, bNHs};

        float hprev[4] = {0.0f, 0.0f, 0.0f, 0.0f};

        #pragma unroll 2
        for (int t = 0; t < LS; ++t) {
            f32x4 aR  = MFMA16(a0, BiR[0], vbR);
            f32x4 aZ  = MFMA16(a0, BiZ[0], vbZ);
            f32x4 aNI = MFMA16(a0, BiN[0], vbNI);
            aR  = MFMA16(a1, BiR[1], aR);
            aZ  = MFMA16(a1, BiZ[1], aZ);
            aNI = MFMA16(a1, BiN[1], aNI);
            f32x4 aNH = vbNH;
            if (t > 0) {
                const unsigned short* hb = hrec + (((t - 1) & 1) << 10);
                bf16x8 h0 = ld_afrag(hb, c, quad, 0);   // pre-relu recurrent
                bf16x8 h1 = ld_afrag(hb, c, quad, 1);
                aR  = MFMA16(h0, BhR[0], aR);
                aZ  = MFMA16(h0, BhZ[0], aZ);
                aNH = MFMA16(h0, BhN[0], aNH);
                aR  = MFMA16(h1, BhR[1], aR);
                aZ  = MFMA16(h1, BhZ[1], aZ);
                aNH = MFMA16(h1, BhN[1], aNH);
            }
            unsigned short* wb = hseq + (t << 10);
            unsigned short* wr = hrec + ((t & 1) << 10);
            #pragma unroll
            for (int i = 0; i < 4; ++i) {
                // scales folded into weights: exp2 directly on accumulators
                float r  = __builtin_amdgcn_rcpf(1.0f + __builtin_amdgcn_exp2f(aR[i]));
                float z  = __builtin_amdgcn_rcpf(1.0f + __builtin_amdgcn_exp2f(aZ[i]));
                float e  = __builtin_amdgcn_exp2f(fmaf(r, aNH[i], aNI[i]));
                float n  = fmaf(-2.0f, __builtin_amdgcn_rcpf(e + 1.0f), 1.0f);
                float hn = fmaf(z, hprev[i] - n, n);
                hprev[i] = hn;
                wr[wIdx[i]] = f2bf_h(hn);                   // pre-relu (recurrence)
                wb[wIdx[i]] = f2bf_h(fmaxf(hn, 0.0f));      // relu'd (next layer)
            }
            // prefetch next input: slot t+1 untouched this step; at t=31 slot 0
            // already holds this layer's relu'd t=0 output = next layer's input
            const unsigned short* nb = hseq + (((t + 1) & 31) << 10);
            a0 = ld_afrag(nb, c, quad, 0);
            a1 = ld_afrag(nb, c, quad, 1);
            __syncthreads();
        }
    }

    // ---- fused epilogue ----
    {   // E1: slow_feat = hseq[31] (already relu'd) @ soW + sob -> stage slot 0
        bf16x8 e0 = ld_afrag(hseq + (31 << 10), c, quad, 0);
        bf16x8 e1 = ld_afrag(hseq + (31 << 10), c, quad, 1);
        bf16x8 Bso[2], Bs2[2];
        #pragma unroll
        for (int kc = 0; kc < 2; ++kc) {
            Bso[kc] = as_frag(wf[(96 + jt)  * 128 + kc * 64 + lane]);
            Bs2[kc] = as_frag(wf[(100 + jt) * 128 + kc * 64 + lane]);
        }
        float sb = sob[col];
        f32x4 accS = (f32x4){sb, sb, sb, sb};
        accS = MFMA16(e0, Bso[0], accS);
        accS = MFMA16(e1, Bso[1], accS);
        #pragma unroll
        for (int i = 0; i < 4; ++i)
            hseq[wIdx[i]] = f2bf_h(accS[i]);     // slot 0 dead: stage slow_feat
        __syncthreads();
        // E2: eps = sf @ s2sW + s2sb -> A_s | g_s (A half pre-scaled by -log2e)
        bf16x8 s0 = ld_afrag(hseq, c, quad, 0);
        bf16x8 s1 = ld_afrag(hseq, c, quad, 1);
        float eb = (jt < 2) ? NLOG2E * s2sb[col] : s2sb[col];
        f32x4 accE = (f32x4){eb, eb, eb, eb};
        accE = MFMA16(s0, Bs2[0], accE);
        accE = MFMA16(s1, Bs2[1], accE);
        #pragma unroll
        for (int i = 0; i < 4; ++i) {
            int row = quad * 4 + i;
            float v = accE[i];
            AG[row * 65 + col] = (jt < 2)
                ? __builtin_amdgcn_rcpf(1.0f + __builtin_amdgcn_exp2f(v)) : v;
        }
    }
    __syncthreads();
    // E3: fast diagonal SSM + overlap-add (16 frames x 32 ch, 2 passes)
    {
        int fch = tid & 31;
        float Gfw = finW[fch], Gbw = finb[fch], cFo = foutW[fch], cfb = foutb[0];
        #pragma unroll
        for (int half = 0; half < 2; ++half) {
            int frame = half * 8 + (tid >> 5);
            int q = seqbase + frame;
            if (q < BS) {        // skip duplicated clamp frames (no double-add)
                int b  = (q >= ns) ? 1 : 0;
                int fi = q - b * ns;
                float cA = AG[frame * 65 + fch];
                float cG = AG[frame * 65 + 32 + fch];
                float Gf = Gfw * cG;
                float Gb = Gbw * cG;
                float h = 0.0f;
                const float* xrow = xs + frame * 33;
                float* op = out + (size_t)b * T + fi * DS;
                #pragma unroll 1
                for (int t = 0; t < LS; ++t) {
                    h = fmaf(cA, h, fmaf(xrow[t], Gf, Gb));
                    float s = h * cFo;
                    s += __shfl_xor(s, 1);
                    s += __shfl_xor(s, 2);
                    s += __shfl_xor(s, 4);
                    s += __shfl_xor(s, 8);
                    s += __shfl_xor(s, 16);
                    if (fch == 0) atomicAdd(&op[t], s + cfb);
                }
            }
        }
    }
}

extern "C" void kernel_launch(void* const* d_in, const int* in_sizes, int n_in,
                              void* d_out, int out_size, void* d_ws, size_t ws_size,
                              hipStream_t stream)
{
    (void)n_in; (void)ws_size;
    const float* x     = (const float*)d_in[0];
    const float* siW   = (const float*)d_in[1];
    const float* sib   = (const float*)d_in[2];
    const float* Wih   = (const float*)d_in[3];
    const float* Whh   = (const float*)d_in[4];
    const float* bih   = (const float*)d_in[5];
    const float* bhh   = (const float*)d_in[6];
    const float* soW   = (const float*)d_in[7];
    const float* sob   = (const float*)d_in[8];
    const float* s2sW  = (const float*)d_in[9];
    const float* s2sb  = (const float*)d_in[10];
    const float* finW  = (const float*)d_in[11];
    const float* finb  = (const float*)d_in[12];
    const float* foutW = (const float*)d_in[13];
    const float* foutb = (const float*)d_in[14];

    int T  = in_sizes[0] / 2;          // B = 2
    int ns = (T - LS) / DS + 1;        // 3999
    int BS = 2 * ns;                   // 7998

    unsigned short* wsW = (unsigned short*)d_ws;   // 104*1024 bf16 = 208 KB

    (void)hipMemsetAsync(d_out, 0, (size_t)out_size * sizeof(float), stream);

    prep_weights<<<dim3(416), dim3(256), 0, stream>>>(Wih, Whh, soW, s2sW, wsW);

    slowfast_fused<<<dim3((BS + 15) / 16), dim3(256), 0, stream>>>(
        x, siW, sib, bih, bhh, sob, s2sb, finW, finb, foutW, foutb,
        wsW, (float*)d_out, T, ns, BS);
}